// Round 3
// baseline (2736.270 us; speedup 1.0000x reference)
//
#include <hip/hip_runtime.h>

#define D 128          // D_IN == D_OUT == 128
#define GEMM_ROWS 32   // rows per block in the dense GEMM
#define NB_MAX 1600    // max coarse buckets (ceil(n_nodes/64))
#define T_TILES 128    // edge tiles for the counting split

// -------- Stage 1: support = x @ W ----------------------------------------
__global__ __launch_bounds__(256) void gcn_gemm(const float* __restrict__ x,
                                                const float* __restrict__ w,
                                                float* __restrict__ support,
                                                int n_nodes) {
    __shared__ float w_lds[D][D];          // 64 KB
    __shared__ float x_lds[GEMM_ROWS][D];  // 16 KB
    const int t = threadIdx.x;

    {
        const float4* w4 = (const float4*)w;
        float4* wl = (float4*)&w_lds[0][0];
#pragma unroll
        for (int i = 0; i < 16; ++i) wl[t + 256 * i] = w4[t + 256 * i];
    }
    const long row_base = (long)blockIdx.x * GEMM_ROWS;
    {
        const float4* x4 = (const float4*)(x + row_base * D);
        float4* xl = (float4*)&x_lds[0][0];
#pragma unroll
        for (int i = 0; i < 4; ++i) xl[t + 256 * i] = x4[t + 256 * i];
    }
    __syncthreads();

    const int c = t & 31;
    const int rg = t >> 5;

    float4 acc[4];
#pragma unroll
    for (int j = 0; j < 4; ++j) acc[j] = make_float4(0.f, 0.f, 0.f, 0.f);

#pragma unroll 4
    for (int k = 0; k < D; ++k) {
        const float4 wv = ((const float4*)&w_lds[k][0])[c];
#pragma unroll
        for (int j = 0; j < 4; ++j) {
            const float xv = x_lds[rg * 4 + j][k];
            acc[j].x += xv * wv.x;
            acc[j].y += xv * wv.y;
            acc[j].z += xv * wv.z;
            acc[j].w += xv * wv.w;
        }
    }

    float4* out4 = (float4*)(support + row_base * D);
#pragma unroll
    for (int j = 0; j < 4; ++j) out4[(rg * 4 + j) * 32 + c] = acc[j];
}

// -------- Stage 2a: per-tile coarse-bucket histogram -----------------------
// M[tile][cb] = count of edges in tile with row>>6 == cb; totals[cb] += count.
__global__ __launch_bounds__(256) void gcn_tile_hist(const int* __restrict__ erow,
                                                     int* __restrict__ M,
                                                     int* __restrict__ totals,
                                                     int n_edges, int tile_sz, int nb) {
    __shared__ int h[NB_MAX];
    const int t = threadIdx.x;
    for (int i = t; i < nb; i += 256) h[i] = 0;
    __syncthreads();
    const int beg = blockIdx.x * tile_sz;
    const int end = min(beg + tile_sz, n_edges);
    for (int e = beg + t; e < end; e += 256)
        atomicAdd(&h[erow[e] >> 6], 1);
    __syncthreads();
    int* Mrow = M + (long)blockIdx.x * nb;
    for (int i = t; i < nb; i += 256) {
        const int cnt = h[i];
        Mrow[i] = cnt;
        if (cnt) atomicAdd(&totals[i], cnt);
    }
}

// -------- Stage 2b: exclusive scan of bucket totals -> base[0..nb] ---------
__global__ __launch_bounds__(1024) void gcn_scan_base(const int* __restrict__ totals,
                                                      int* __restrict__ base, int nb) {
    __shared__ int sdata[1024];
    const int t = threadIdx.x;
    const int chunk = (nb + 1023) >> 10;
    const int beg = min(t * chunk, nb);
    const int end = min(beg + chunk, nb);

    int sum = 0;
    for (int i = beg; i < end; ++i) sum += totals[i];
    sdata[t] = sum;
    __syncthreads();
    for (int off = 1; off < 1024; off <<= 1) {
        const int v = (t >= off) ? sdata[t - off] : 0;
        __syncthreads();
        sdata[t] += v;
        __syncthreads();
    }
    int running = sdata[t] - sum;
    if (t == 1023) base[nb] = sdata[1023];
    for (int i = beg; i < end; ++i) {
        const int c = totals[i];
        base[i] = running;
        running += c;
    }
}

// -------- Stage 2c: per-(tile,bucket) start offsets (in-place in M) --------
// M[tile][cb] := base[cb] + sum_{t'<tile} M[t'][cb]
__global__ __launch_bounds__(256) void gcn_tile_offsets(int* __restrict__ M,
                                                        const int* __restrict__ base,
                                                        int nb, int n_tiles) {
    const int cb = blockIdx.x * 256 + threadIdx.x;
    if (cb >= nb) return;
    int running = base[cb];
    for (int tt = 0; tt < n_tiles; ++tt) {
        int* p = M + (long)tt * nb + cb;   // coalesced across threads
        const int c = *p;
        *p = running;
        running += c;
    }
}

// -------- Stage 2d: scatter edges into bucket-grouped array ----------------
// packed[pos] = (row_local<<17 | col, val). Runs per (tile,bucket) are
// contiguous => ~1x write amplification (vs 8x for the exact-CSR fill).
__global__ __launch_bounds__(256) void gcn_split(const int* __restrict__ erow,
                                                 const int* __restrict__ ecol,
                                                 const float* __restrict__ eval,
                                                 const int* __restrict__ M,
                                                 int2* __restrict__ packed,
                                                 int n_edges, int tile_sz, int nb) {
    __shared__ int off[NB_MAX];
    const int t = threadIdx.x;
    const int* Mrow = M + (long)blockIdx.x * nb;
    for (int i = t; i < nb; i += 256) off[i] = Mrow[i];
    __syncthreads();
    const int beg = blockIdx.x * tile_sz;
    const int end = min(beg + tile_sz, n_edges);
    for (int e = beg + t; e < end; e += 256) {
        const int r = erow[e];
        const int pos = atomicAdd(&off[r >> 6], 1);
        const unsigned key = ((unsigned)(r & 63) << 17) | (unsigned)ecol[e];
        packed[pos] = make_int2((int)key, __float_as_int(eval[e]));
    }
}

// -------- Stage 3: per-bucket aggregate with LDS accumulators --------------
// Block cb owns rows [cb*64, cb*64+64). acc[rl][c], c = k*32+lane so the
// ds_add_f32 bank pattern is lane->bank identity (2-way across wave = free).
__global__ __launch_bounds__(256) void gcn_aggregate(const float* __restrict__ support,
                                                     const int2* __restrict__ packed,
                                                     const int* __restrict__ base,
                                                     const float* __restrict__ bias,
                                                     float* __restrict__ out,
                                                     int n_nodes) {
    __shared__ float acc[64 * D];   // 32 KB
    __shared__ int2 ebuf[256];      // 2 KB
    const int t = threadIdx.x;

    float4* acc4 = (float4*)acc;
    for (int i = t; i < 64 * 32; i += 256) acc4[i] = make_float4(0.f, 0.f, 0.f, 0.f);
    __syncthreads();

    const int cb = blockIdx.x;
    const int start = base[cb];
    const int stop = base[cb + 1];
    const int lane = t & 31;
    const int g = t >> 5;           // 8 groups of 32 lanes

    for (int b = start; b < stop; b += 256) {
        const int n = min(256, stop - b);
        if (t < n) ebuf[t] = packed[b + t];
        __syncthreads();
        const int jend = min(g * 32 + 32, n);
        for (int j = g * 32; j < jend; ++j) {
            const int2 ed = ebuf[j];                 // LDS broadcast
            const unsigned key = (unsigned)ed.x;
            const int col = (int)(key & 0x1FFFFu);
            const int rl = (int)(key >> 17);
            const float v = __int_as_float(ed.y);
            const float* srow = support + (long)col * D;
            float* arow = acc + rl * D;
#pragma unroll
            for (int k = 0; k < 4; ++k) {
                const float s = srow[k * 32 + lane]; // 128B coalesced per group
                atomicAdd(&arow[k * 32 + lane], v * s);
            }
        }
        __syncthreads();
    }

    // out[r] = acc[rl] + bias  (columns in interleaved c = k*32+lane order,
    // which is just linear memory order -- write as float4)
    const float4* b4 = (const float4*)bias;
    for (int i = t; i < 64 * 32; i += 256) {
        const int rl = i >> 5;
        const int ln = i & 31;
        const int r = cb * 64 + rl;
        if (r < n_nodes) {
            float4 a = acc4[i];
            const float4 bb = b4[ln];
            a.x += bb.x; a.y += bb.y; a.z += bb.z; a.w += bb.w;
            ((float4*)out)[(long)r * 32 + ln] = a;
        }
    }
}

extern "C" void kernel_launch(void* const* d_in, const int* in_sizes, int n_in,
                              void* d_out, int out_size, void* d_ws, size_t ws_size,
                              hipStream_t stream) {
    const float* x    = (const float*)d_in[0];
    const float* w    = (const float*)d_in[1];
    const float* bias = (const float*)d_in[2];
    const int* erow   = (const int*)d_in[3];
    const int* ecol   = (const int*)d_in[4];
    const float* eval = (const float*)d_in[5];

    const int n_nodes = in_sizes[0] / D;   // 100000
    const int n_edges = in_sizes[3];       // 3200000
    const int nb = (n_nodes + 63) >> 6;    // 1563 coarse buckets
    const int tile_sz = (n_edges + T_TILES - 1) / T_TILES;

    // Workspace: support | packed | M | totals | base  (~78 MB)
    char* ws = (char*)d_ws;
    float* support = (float*)ws;
    size_t off = (size_t)n_nodes * D * sizeof(float);
    int2* packed = (int2*)(ws + off);
    off += (size_t)n_edges * sizeof(int2);
    int* M = (int*)(ws + off);
    off += (size_t)T_TILES * nb * sizeof(int);
    int* totals = (int*)(ws + off);
    off += (size_t)(nb + 1) * sizeof(int);
    int* base = (int*)(ws + off);

    float* out = (float*)d_out;

    // 1. support = x @ W
    gcn_gemm<<<(n_nodes + GEMM_ROWS - 1) / GEMM_ROWS, 256, 0, stream>>>(
        x, w, support, n_nodes);

    // 2. Coarse counting split (bucket = row>>6)
    hipMemsetAsync(totals, 0, (size_t)(nb + 1) * sizeof(int), stream);
    gcn_tile_hist<<<T_TILES, 256, 0, stream>>>(erow, M, totals, n_edges, tile_sz, nb);
    gcn_scan_base<<<1, 1024, 0, stream>>>(totals, base, nb);
    gcn_tile_offsets<<<(nb + 255) / 256, 256, 0, stream>>>(M, base, nb, T_TILES);
    gcn_split<<<T_TILES, 256, 0, stream>>>(erow, ecol, eval, M, packed,
                                           n_edges, tile_sz, nb);

    // 3. Per-bucket aggregate (LDS accumulators), fused bias + store
    gcn_aggregate<<<nb, 256, 0, stream>>>(support, packed, base, bias, out, n_nodes);
}

// Round 4
// 770.311 us; speedup vs baseline: 3.5522x; 3.5522x over previous
//
#include <hip/hip_runtime.h>

#define D 128          // D_IN == D_OUT == 128
#define GEMM_ROWS 32   // rows per block in the dense GEMM

// -------- Stage 1: support = x @ W ----------------------------------------
__global__ __launch_bounds__(256) void gcn_gemm(const float* __restrict__ x,
                                                const float* __restrict__ w,
                                                float* __restrict__ support,
                                                int n_nodes) {
    __shared__ float w_lds[D][D];          // 64 KB
    __shared__ float x_lds[GEMM_ROWS][D];  // 16 KB
    const int t = threadIdx.x;

    {
        const float4* w4 = (const float4*)w;
        float4* wl = (float4*)&w_lds[0][0];
#pragma unroll
        for (int i = 0; i < 16; ++i) wl[t + 256 * i] = w4[t + 256 * i];
    }
    const long row_base = (long)blockIdx.x * GEMM_ROWS;
    {
        const float4* x4 = (const float4*)(x + row_base * D);
        float4* xl = (float4*)&x_lds[0][0];
#pragma unroll
        for (int i = 0; i < 4; ++i) xl[t + 256 * i] = x4[t + 256 * i];
    }
    __syncthreads();

    const int c = t & 31;
    const int rg = t >> 5;

    float4 acc[4];
#pragma unroll
    for (int j = 0; j < 4; ++j) acc[j] = make_float4(0.f, 0.f, 0.f, 0.f);

#pragma unroll 4
    for (int k = 0; k < D; ++k) {
        const float4 wv = ((const float4*)&w_lds[k][0])[c];
#pragma unroll
        for (int j = 0; j < 4; ++j) {
            const float xv = x_lds[rg * 4 + j][k];
            acc[j].x += xv * wv.x;
            acc[j].y += xv * wv.y;
            acc[j].z += xv * wv.z;
            acc[j].w += xv * wv.w;
        }
    }

    float4* out4 = (float4*)(support + row_base * D);
#pragma unroll
    for (int j = 0; j < 4; ++j) out4[(rg * 4 + j) * 32 + c] = acc[j];
}

// -------- Stage 2: histogram of edge rows into rp[0..n) --------------------
__global__ __launch_bounds__(256) void gcn_hist(const int* __restrict__ erow,
                                                int* __restrict__ rp,
                                                int n_edges) {
    const int e = blockIdx.x * blockDim.x + threadIdx.x;
    if (e < n_edges) atomicAdd(&rp[erow[e]], 1);
}

// -------- Stage 3: parallel exclusive scan (3 kernels, 512 elems/block) ----
__global__ __launch_bounds__(256) void gcn_scan_partial(const int* __restrict__ rp,
                                                        int* __restrict__ partial,
                                                        int n) {
    __shared__ int s[256];
    const int t = threadIdx.x;
    const int i0 = blockIdx.x * 512 + t * 2;
    int sum = 0;
    if (i0 < n) sum += rp[i0];
    if (i0 + 1 < n) sum += rp[i0 + 1];
    s[t] = sum;
    __syncthreads();
    for (int off = 128; off > 0; off >>= 1) {
        if (t < off) s[t] += s[t + off];
        __syncthreads();
    }
    if (t == 0) partial[blockIdx.x] = s[0];
}

__global__ __launch_bounds__(256) void gcn_scan_tops(int* __restrict__ partial,
                                                     int nparts) {
    __shared__ int s[256];
    const int t = threadIdx.x;
    const int v = (t < nparts) ? partial[t] : 0;
    s[t] = v;
    __syncthreads();
    for (int off = 1; off < 256; off <<= 1) {
        const int u = (t >= off) ? s[t - off] : 0;
        __syncthreads();
        s[t] += u;
        __syncthreads();
    }
    if (t < nparts) partial[t] = s[t] - v;  // exclusive
}

__global__ __launch_bounds__(256) void gcn_scan_final(int* __restrict__ rp,
                                                      const int* __restrict__ partial,
                                                      int n) {
    __shared__ int s[256];
    const int t = threadIdx.x;
    const int i0 = blockIdx.x * 512 + t * 2;
    const int c0 = (i0 < n) ? rp[i0] : 0;
    const int c1 = (i0 + 1 < n) ? rp[i0 + 1] : 0;
    const int tsum = c0 + c1;
    s[t] = tsum;
    __syncthreads();
    for (int off = 1; off < 256; off <<= 1) {
        const int u = (t >= off) ? s[t - off] : 0;
        __syncthreads();
        s[t] += u;
        __syncthreads();
    }
    const int base = partial[blockIdx.x] + s[t] - tsum;
    if (i0 < n) rp[i0] = base;
    if (i0 + 1 < n) rp[i0 + 1] = base + c0;
}

// -------- Stage 4: bucket edges by row (CSR fill) --------------------------
// After this kernel, rp[r] == end-offset of row r.
__global__ __launch_bounds__(256) void gcn_fill(const int* __restrict__ erow,
                                                const int* __restrict__ ecol,
                                                const float* __restrict__ eval,
                                                int* __restrict__ rp,
                                                int2* __restrict__ packed,
                                                int n_edges) {
    const int e = blockIdx.x * blockDim.x + threadIdx.x;
    if (e >= n_edges) return;
    const int r = erow[e];
    const int pos = atomicAdd(&rp[r], 1);
    packed[pos] = make_int2(ecol[e], __float_as_int(eval[e]));
}

// -------- Stage 5: out[r] = bias + sum_{e in row r} v_e * support[c_e] -----
// ONE FULL 64-LANE WAVE per row (no half-wave divergence, no LDS, no
// barriers). float2 per lane: 128 cols = 64 lanes x 2. One coalesced 512B
// load per edge; 64-edge batches broadcast via width-64 shfl.
__global__ __launch_bounds__(512) void gcn_aggregate(const float* __restrict__ support,
                                                     const int2* __restrict__ packed,
                                                     const int* __restrict__ rp,
                                                     const float* __restrict__ bias,
                                                     float* __restrict__ out,
                                                     int n_nodes) {
    const int t = threadIdx.x;
    const int lane = t & 63;
    const int r = blockIdx.x * 8 + (t >> 6);   // 8 waves per block
    if (r >= n_nodes) return;

    const int start = (r == 0) ? 0 : rp[r - 1];
    const int end = rp[r];

    float2 acc = ((const float2*)bias)[lane];
    const float2* s2 = (const float2*)support;

    for (int b = start; b < end; b += 64) {
        const int nn = min(64, end - b);
        int2 ed = make_int2(0, 0);
        if (lane < nn) ed = packed[b + lane];   // coalesced 8B/lane
#pragma unroll 4
        for (int j = 0; j < nn; ++j) {
            const int c = __shfl(ed.x, j, 64);
            const float v = __int_as_float(__shfl(ed.y, j, 64));
            const float2 s = s2[(long)c * 64 + lane];
            acc.x += v * s.x;
            acc.y += v * s.y;
        }
    }
    ((float2*)out)[(long)r * 64 + lane] = acc;
}

extern "C" void kernel_launch(void* const* d_in, const int* in_sizes, int n_in,
                              void* d_out, int out_size, void* d_ws, size_t ws_size,
                              hipStream_t stream) {
    const float* x    = (const float*)d_in[0];
    const float* w    = (const float*)d_in[1];
    const float* bias = (const float*)d_in[2];
    const int* erow   = (const int*)d_in[3];
    const int* ecol   = (const int*)d_in[4];
    const float* eval = (const float*)d_in[5];

    const int n_nodes = in_sizes[0] / D;   // 100000
    const int n_edges = in_sizes[3];       // 3200000

    // Workspace: support | rp | packed | partial
    char* ws = (char*)d_ws;
    float* support = (float*)ws;
    size_t off = (size_t)n_nodes * D * sizeof(float);
    int* rp = (int*)(ws + off);
    off += ((size_t)(n_nodes + 1) * sizeof(int) + 15) & ~(size_t)15;
    int2* packed = (int2*)(ws + off);
    off += (size_t)n_edges * sizeof(int2);
    int* partial = (int*)(ws + off);

    float* out = (float*)d_out;

    const int n_scan_blocks = (n_nodes + 511) / 512;   // 196

    // 1. support = x @ W
    gcn_gemm<<<(n_nodes + GEMM_ROWS - 1) / GEMM_ROWS, 256, 0, stream>>>(
        x, w, support, n_nodes);

    // 2-4. Build CSR: zero counts, histogram, parallel scan, fill
    hipMemsetAsync(rp, 0, (size_t)(n_nodes + 1) * sizeof(int), stream);
    gcn_hist<<<(n_edges + 255) / 256, 256, 0, stream>>>(erow, rp, n_edges);
    gcn_scan_partial<<<n_scan_blocks, 256, 0, stream>>>(rp, partial, n_nodes);
    gcn_scan_tops<<<1, 256, 0, stream>>>(partial, n_scan_blocks);
    gcn_scan_final<<<n_scan_blocks, 256, 0, stream>>>(rp, partial, n_nodes);
    gcn_fill<<<(n_edges + 255) / 256, 256, 0, stream>>>(
        erow, ecol, eval, rp, packed, n_edges);

    // 5. Gather-aggregate: one 64-lane wave per row
    gcn_aggregate<<<(n_nodes + 7) / 8, 512, 0, stream>>>(
        support, packed, rp, bias, out, n_nodes);
}

// Round 5
// 525.622 us; speedup vs baseline: 5.2058x; 1.4655x over previous
//
#include <hip/hip_runtime.h>

#define D 128          // D_IN == D_OUT == 128
#define GEMM_ROWS 32   // rows per block in the dense GEMM
#define NB_MAX 1600    // max coarse buckets (ceil(n_nodes/64))
#define T_TILES 256    // edge tiles for the counting split

// -------- Stage 1: support = x @ W ----------------------------------------
__global__ __launch_bounds__(256) void gcn_gemm(const float* __restrict__ x,
                                                const float* __restrict__ w,
                                                float* __restrict__ support,
                                                int n_nodes) {
    __shared__ float w_lds[D][D];          // 64 KB
    __shared__ float x_lds[GEMM_ROWS][D];  // 16 KB
    const int t = threadIdx.x;

    {
        const float4* w4 = (const float4*)w;
        float4* wl = (float4*)&w_lds[0][0];
#pragma unroll
        for (int i = 0; i < 16; ++i) wl[t + 256 * i] = w4[t + 256 * i];
    }
    const long row_base = (long)blockIdx.x * GEMM_ROWS;
    {
        const float4* x4 = (const float4*)(x + row_base * D);
        float4* xl = (float4*)&x_lds[0][0];
#pragma unroll
        for (int i = 0; i < 4; ++i) xl[t + 256 * i] = x4[t + 256 * i];
    }
    __syncthreads();

    const int c = t & 31;
    const int rg = t >> 5;

    float4 acc[4];
#pragma unroll
    for (int j = 0; j < 4; ++j) acc[j] = make_float4(0.f, 0.f, 0.f, 0.f);

#pragma unroll 4
    for (int k = 0; k < D; ++k) {
        const float4 wv = ((const float4*)&w_lds[k][0])[c];
#pragma unroll
        for (int j = 0; j < 4; ++j) {
            const float xv = x_lds[rg * 4 + j][k];
            acc[j].x += xv * wv.x;
            acc[j].y += xv * wv.y;
            acc[j].z += xv * wv.z;
            acc[j].w += xv * wv.w;
        }
    }

    float4* out4 = (float4*)(support + row_base * D);
#pragma unroll
    for (int j = 0; j < 4; ++j) out4[(rg * 4 + j) * 32 + c] = acc[j];
}

// -------- Stage 2a: per-tile coarse-bucket histogram (raw counts) ----------
__global__ __launch_bounds__(1024) void gcn_tile_hist(const int* __restrict__ erow,
                                                      int* __restrict__ M,
                                                      int n_edges, int tile_sz, int nb) {
    __shared__ int h[NB_MAX];
    const int t = threadIdx.x;
    for (int i = t; i < nb; i += 1024) h[i] = 0;
    __syncthreads();
    const int beg = blockIdx.x * tile_sz;
    const int end = min(beg + tile_sz, n_edges);
    for (int e = beg + t; e < end; e += 1024)
        atomicAdd(&h[erow[e] >> 6], 1);
    __syncthreads();
    int* Mrow = M + (long)blockIdx.x * nb;
    for (int i = t; i < nb; i += 1024) Mrow[i] = h[i];
}

// -------- Stage 2b: vertical exclusive scan per bucket; totals out ---------
__global__ __launch_bounds__(256) void gcn_tile_offsets(int* __restrict__ M,
                                                        int* __restrict__ totals,
                                                        int nb) {
    const int cb = blockIdx.x * 256 + threadIdx.x;
    if (cb >= nb) return;
    int running = 0;
#pragma unroll 8
    for (int tt = 0; tt < T_TILES; ++tt) {
        int* p = M + (long)tt * nb + cb;   // coalesced across threads
        const int c = *p;
        *p = running;
        running += c;
    }
    totals[cb] = running;
}

// -------- Stage 2c: exclusive scan of bucket totals -> base[0..nb] ---------
__global__ __launch_bounds__(1024) void gcn_scan_base(const int* __restrict__ totals,
                                                      int* __restrict__ base, int nb) {
    __shared__ int sdata[1024];
    const int t = threadIdx.x;
    const int chunk = (nb + 1023) >> 10;
    const int beg = min(t * chunk, nb);
    const int end = min(beg + chunk, nb);

    int sum = 0;
    for (int i = beg; i < end; ++i) sum += totals[i];
    sdata[t] = sum;
    __syncthreads();
    for (int off = 1; off < 1024; off <<= 1) {
        const int v = (t >= off) ? sdata[t - off] : 0;
        __syncthreads();
        sdata[t] += v;
        __syncthreads();
    }
    int running = sdata[t] - sum;
    if (t == 1023) base[nb] = sdata[1023];
    for (int i = beg; i < end; ++i) {
        const int c = totals[i];
        base[i] = running;
        running += c;
    }
}

// -------- Stage 2d: scatter edges into bucket-grouped tmp ------------------
// tmp[pos] = (row_local<<17 | col, val). Per-(tile,bucket) runs contiguous.
__global__ __launch_bounds__(1024) void gcn_split(const int* __restrict__ erow,
                                                  const int* __restrict__ ecol,
                                                  const float* __restrict__ eval,
                                                  const int* __restrict__ M,
                                                  const int* __restrict__ base,
                                                  int2* __restrict__ tmp,
                                                  int n_edges, int tile_sz, int nb) {
    __shared__ int off[NB_MAX];
    const int t = threadIdx.x;
    const int* Mrow = M + (long)blockIdx.x * nb;
    for (int i = t; i < nb; i += 1024) off[i] = Mrow[i] + base[i];
    __syncthreads();
    const int beg = blockIdx.x * tile_sz;
    const int end = min(beg + tile_sz, n_edges);
    for (int e = beg + t; e < end; e += 1024) {
        const int r = erow[e];
        const int pos = atomicAdd(&off[r >> 6], 1);
        const unsigned key = ((unsigned)(r & 63) << 17) | (unsigned)ecol[e];
        tmp[pos] = make_int2((int)key, __float_as_int(eval[e]));
    }
}

// -------- Stage 2e: per-bucket counting sort -> exact CSR + rp -------------
// Block cb sorts its ~2048-edge run into packed[] (writes confined to its own
// ~16 KB region -> L2-local, ~1x write amp) and derives rp start offsets.
__global__ __launch_bounds__(256) void gcn_bucket_fill(const int2* __restrict__ tmp,
                                                       const int* __restrict__ base,
                                                       int2* __restrict__ packed,
                                                       int* __restrict__ rp,
                                                       int n_nodes) {
    __shared__ int hist[64];
    __shared__ int offs[64];
    const int t = threadIdx.x;
    const int cb = blockIdx.x;
    const int start = base[cb];
    const int stop = base[cb + 1];

    if (t < 64) hist[t] = 0;
    __syncthreads();
    for (int i = start + t; i < stop; i += 256)
        atomicAdd(&hist[(unsigned)tmp[i].x >> 17], 1);
    __syncthreads();
    if (t == 0) {
        int run = 0;
#pragma unroll
        for (int i = 0; i < 64; ++i) { offs[i] = run; run += hist[i]; }
    }
    __syncthreads();
    if (t < 64) {
        const int r = cb * 64 + t;
        if (r < n_nodes) rp[r] = start + offs[t];
    }
    __syncthreads();
    for (int i = start + t; i < stop; i += 256) {
        const int2 ed = tmp[i];                       // L2-hit (2nd pass)
        const int rl = (int)((unsigned)ed.x >> 17);
        const int pos = start + atomicAdd(&offs[rl], 1);
        packed[pos] = make_int2(ed.x & 0x1FFFF, ed.y);
    }
}

// -------- Stage 3: out[r] = bias + sum_{e in row r} v_e * support[c_e] -----
// One full 64-lane wave per row; float2/lane (128 cols = 64 x 2).
__global__ __launch_bounds__(512) void gcn_aggregate(const float* __restrict__ support,
                                                     const int2* __restrict__ packed,
                                                     const int* __restrict__ rp,
                                                     const float* __restrict__ bias,
                                                     float* __restrict__ out,
                                                     int n_nodes, int n_edges) {
    const int t = threadIdx.x;
    const int lane = t & 63;
    const int r = blockIdx.x * 8 + (t >> 6);   // 8 waves per block
    if (r >= n_nodes) return;

    const int start = rp[r];
    const int end = (r + 1 < n_nodes) ? rp[r + 1] : n_edges;

    float2 acc = ((const float2*)bias)[lane];
    const float2* s2 = (const float2*)support;

    for (int b = start; b < end; b += 64) {
        const int nn = min(64, end - b);
        int2 ed = make_int2(0, 0);
        if (lane < nn) ed = packed[b + lane];   // coalesced 8B/lane
#pragma unroll 4
        for (int j = 0; j < nn; ++j) {
            const int c = __shfl(ed.x, j, 64);
            const float v = __int_as_float(__shfl(ed.y, j, 64));
            const float2 s = s2[(long)c * 64 + lane];
            acc.x += v * s.x;
            acc.y += v * s.y;
        }
    }
    ((float2*)out)[(long)r * 64 + lane] = acc;
}

extern "C" void kernel_launch(void* const* d_in, const int* in_sizes, int n_in,
                              void* d_out, int out_size, void* d_ws, size_t ws_size,
                              hipStream_t stream) {
    const float* x    = (const float*)d_in[0];
    const float* w    = (const float*)d_in[1];
    const float* bias = (const float*)d_in[2];
    const int* erow   = (const int*)d_in[3];
    const int* ecol   = (const int*)d_in[4];
    const float* eval = (const float*)d_in[5];

    const int n_nodes = in_sizes[0] / D;   // 100000
    const int n_edges = in_sizes[3];       // 3200000
    const int nb = (n_nodes + 63) >> 6;    // 1563 coarse buckets
    const int tile_sz = (n_edges + T_TILES - 1) / T_TILES;

    // Persistent workspace (needed by final aggregate): support | packed | rp
    char* ws = (char*)d_ws;
    float* support = (float*)ws;
    size_t off = (size_t)n_nodes * D * sizeof(float);
    int2* packed = (int2*)(ws + off);
    off += (size_t)n_edges * sizeof(int2);
    int* rp = (int*)(ws + off);

    // Transient buffers live in d_out (dead before aggregate writes it):
    // tmp (25.6 MB) | M (1.6 MB) | totals | base
    char* ob = (char*)d_out;
    int2* tmp = (int2*)ob;
    size_t ooff = (size_t)n_edges * sizeof(int2);
    int* M = (int*)(ob + ooff);
    ooff += (size_t)T_TILES * nb * sizeof(int);
    int* totals = (int*)(ob + ooff);
    ooff += (size_t)(nb + 1) * sizeof(int);
    int* base = (int*)(ob + ooff);

    float* out = (float*)d_out;

    // 1. support = x @ W
    gcn_gemm<<<(n_nodes + GEMM_ROWS - 1) / GEMM_ROWS, 256, 0, stream>>>(
        x, w, support, n_nodes);

    // 2. Two-phase counting split -> exact CSR (packed, rp)
    gcn_tile_hist<<<T_TILES, 1024, 0, stream>>>(erow, M, n_edges, tile_sz, nb);
    gcn_tile_offsets<<<(nb + 255) / 256, 256, 0, stream>>>(M, totals, nb);
    gcn_scan_base<<<1, 1024, 0, stream>>>(totals, base, nb);
    gcn_split<<<T_TILES, 1024, 0, stream>>>(erow, ecol, eval, M, base, tmp,
                                            n_edges, tile_sz, nb);
    gcn_bucket_fill<<<nb, 256, 0, stream>>>(tmp, base, packed, rp, n_nodes);

    // 3. Gather-aggregate: one 64-lane wave per row
    gcn_aggregate<<<(n_nodes + 7) / 8, 512, 0, stream>>>(
        support, packed, rp, bias, out, n_nodes, n_edges);
}

// Round 6
// 494.556 us; speedup vs baseline: 5.5328x; 1.0628x over previous
//
#include <hip/hip_runtime.h>

#define D 128          // D_IN == D_OUT == 128
#define GEMM_ROWS 32   // rows per block in the dense GEMM
#define NB_MAX 1600    // max coarse buckets (ceil(n_nodes/64))
#define T_TILES 256    // edge tiles for the counting split

// round-to-nearest-even fp32 -> bf16 (as low 16 bits)
__device__ __forceinline__ unsigned bf16_rne(float f) {
    const unsigned u = __float_as_uint(f);
    return (u + 0x7FFFu + ((u >> 16) & 1u)) >> 16;
}

// -------- Stage 1: support = x @ W  (fp32 compute, bf16 output) ------------
__global__ __launch_bounds__(256) void gcn_gemm(const float* __restrict__ x,
                                                const float* __restrict__ w,
                                                unsigned* __restrict__ support, // bf16x2 units
                                                int n_nodes) {
    __shared__ float w_lds[D][D];          // 64 KB
    __shared__ float x_lds[GEMM_ROWS][D];  // 16 KB
    const int t = threadIdx.x;

    {
        const float4* w4 = (const float4*)w;
        float4* wl = (float4*)&w_lds[0][0];
#pragma unroll
        for (int i = 0; i < 16; ++i) wl[t + 256 * i] = w4[t + 256 * i];
    }
    const long row_base = (long)blockIdx.x * GEMM_ROWS;
    {
        const float4* x4 = (const float4*)(x + row_base * D);
        float4* xl = (float4*)&x_lds[0][0];
#pragma unroll
        for (int i = 0; i < 4; ++i) xl[t + 256 * i] = x4[t + 256 * i];
    }
    __syncthreads();

    const int c = t & 31;   // cols 4c..4c+3
    const int rg = t >> 5;  // rows rg*4..rg*4+3

    float4 acc[4];
#pragma unroll
    for (int j = 0; j < 4; ++j) acc[j] = make_float4(0.f, 0.f, 0.f, 0.f);

#pragma unroll 4
    for (int k = 0; k < D; ++k) {
        const float4 wv = ((const float4*)&w_lds[k][0])[c];
#pragma unroll
        for (int j = 0; j < 4; ++j) {
            const float xv = x_lds[rg * 4 + j][k];
            acc[j].x += xv * wv.x;
            acc[j].y += xv * wv.y;
            acc[j].z += xv * wv.z;
            acc[j].w += xv * wv.w;
        }
    }

    // Store bf16: row r occupies 64 uints (bf16x2); thread covers uints 2c,2c+1
#pragma unroll
    for (int j = 0; j < 4; ++j) {
        const long r = row_base + rg * 4 + j;
        uint2 pk;
        pk.x = bf16_rne(acc[j].x) | (bf16_rne(acc[j].y) << 16);
        pk.y = bf16_rne(acc[j].z) | (bf16_rne(acc[j].w) << 16);
        ((uint2*)support)[r * 32 + c] = pk;
    }
}

// -------- Stage 2a: per-tile coarse-bucket histogram (raw counts) ----------
__global__ __launch_bounds__(1024) void gcn_tile_hist(const int* __restrict__ erow,
                                                      int* __restrict__ M,
                                                      int n_edges, int tile_sz, int nb) {
    __shared__ int h[NB_MAX];
    const int t = threadIdx.x;
    for (int i = t; i < nb; i += 1024) h[i] = 0;
    __syncthreads();
    const int beg = blockIdx.x * tile_sz;
    const int end = min(beg + tile_sz, n_edges);
    for (int e = beg + t; e < end; e += 1024)
        atomicAdd(&h[erow[e] >> 6], 1);
    __syncthreads();
    int* Mrow = M + (long)blockIdx.x * nb;
    for (int i = t; i < nb; i += 1024) Mrow[i] = h[i];
}

// -------- Stage 2b: vertical exclusive scan per bucket; totals out ---------
__global__ __launch_bounds__(256) void gcn_tile_offsets(int* __restrict__ M,
                                                        int* __restrict__ totals,
                                                        int nb) {
    const int cb = blockIdx.x * 256 + threadIdx.x;
    if (cb >= nb) return;
    int running = 0;
#pragma unroll 8
    for (int tt = 0; tt < T_TILES; ++tt) {
        int* p = M + (long)tt * nb + cb;   // coalesced across threads
        const int c = *p;
        *p = running;
        running += c;
    }
    totals[cb] = running;
}

// -------- Stage 2c: exclusive scan of bucket totals -> base[0..nb] ---------
__global__ __launch_bounds__(1024) void gcn_scan_base(const int* __restrict__ totals,
                                                      int* __restrict__ base, int nb) {
    __shared__ int sdata[1024];
    const int t = threadIdx.x;
    const int chunk = (nb + 1023) >> 10;
    const int beg = min(t * chunk, nb);
    const int end = min(beg + chunk, nb);

    int sum = 0;
    for (int i = beg; i < end; ++i) sum += totals[i];
    sdata[t] = sum;
    __syncthreads();
    for (int off = 1; off < 1024; off <<= 1) {
        const int v = (t >= off) ? sdata[t - off] : 0;
        __syncthreads();
        sdata[t] += v;
        __syncthreads();
    }
    int running = sdata[t] - sum;
    if (t == 1023) base[nb] = sdata[1023];
    for (int i = beg; i < end; ++i) {
        const int c = totals[i];
        base[i] = running;
        running += c;
    }
}

// -------- Stage 2d: scatter edges into bucket-grouped tmp ------------------
__global__ __launch_bounds__(1024) void gcn_split(const int* __restrict__ erow,
                                                  const int* __restrict__ ecol,
                                                  const float* __restrict__ eval,
                                                  const int* __restrict__ M,
                                                  const int* __restrict__ base,
                                                  int2* __restrict__ tmp,
                                                  int n_edges, int tile_sz, int nb) {
    __shared__ int off[NB_MAX];
    const int t = threadIdx.x;
    const int* Mrow = M + (long)blockIdx.x * nb;
    for (int i = t; i < nb; i += 1024) off[i] = Mrow[i] + base[i];
    __syncthreads();
    const int beg = blockIdx.x * tile_sz;
    const int end = min(beg + tile_sz, n_edges);
    for (int e = beg + t; e < end; e += 1024) {
        const int r = erow[e];
        const int pos = atomicAdd(&off[r >> 6], 1);
        const unsigned key = ((unsigned)(r & 63) << 17) | (unsigned)ecol[e];
        tmp[pos] = make_int2((int)key, __float_as_int(eval[e]));
    }
}

// -------- Stage 2e: per-bucket counting sort -> exact CSR + rp -------------
__global__ __launch_bounds__(256) void gcn_bucket_fill(const int2* __restrict__ tmp,
                                                       const int* __restrict__ base,
                                                       int2* __restrict__ packed,
                                                       int* __restrict__ rp,
                                                       int n_nodes) {
    __shared__ int hist[64];
    __shared__ int offs[64];
    const int t = threadIdx.x;
    const int cb = blockIdx.x;
    const int start = base[cb];
    const int stop = base[cb + 1];

    if (t < 64) hist[t] = 0;
    __syncthreads();
    for (int i = start + t; i < stop; i += 256)
        atomicAdd(&hist[(unsigned)tmp[i].x >> 17], 1);
    __syncthreads();
    if (t == 0) {
        int run = 0;
#pragma unroll
        for (int i = 0; i < 64; ++i) { offs[i] = run; run += hist[i]; }
    }
    __syncthreads();
    if (t < 64) {
        const int r = cb * 64 + t;
        if (r < n_nodes) rp[r] = start + offs[t];
    }
    __syncthreads();
    for (int i = start + t; i < stop; i += 256) {
        const int2 ed = tmp[i];
        const int rl = (int)((unsigned)ed.x >> 17);
        const int pos = start + atomicAdd(&offs[rl], 1);
        packed[pos] = make_int2(ed.x & 0x1FFFF, ed.y);
    }
}

// -------- Stage 3: out[r] = bias + sum v_e * support[c_e]  (bf16 gathers) --
// One full 64-lane wave per row; one bf16x2 dword per lane (256B/row gather).
__global__ __launch_bounds__(512) void gcn_aggregate(const unsigned* __restrict__ support,
                                                     const int2* __restrict__ packed,
                                                     const int* __restrict__ rp,
                                                     const float* __restrict__ bias,
                                                     float* __restrict__ out,
                                                     int n_nodes, int n_edges) {
    const int t = threadIdx.x;
    const int lane = t & 63;
    const int r = blockIdx.x * 8 + (t >> 6);   // 8 waves per block
    if (r >= n_nodes) return;

    const int start = rp[r];
    const int end = (r + 1 < n_nodes) ? rp[r + 1] : n_edges;

    float2 acc = ((const float2*)bias)[lane];   // cols 2*lane, 2*lane+1

    for (int b = start; b < end; b += 64) {
        const int nn = min(64, end - b);
        int2 ed = make_int2(0, 0);
        if (lane < nn) ed = packed[b + lane];   // coalesced 8B/lane
#pragma unroll 4
        for (int j = 0; j < nn; ++j) {
            const int c = __shfl(ed.x, j, 64);
            const float v = __int_as_float(__shfl(ed.y, j, 64));
            const unsigned pv = support[(long)c * 64 + lane];  // 256B coalesced
            acc.x += v * __uint_as_float(pv << 16);
            acc.y += v * __uint_as_float(pv & 0xFFFF0000u);
        }
    }
    ((float2*)out)[(long)r * 64 + lane] = acc;
}

extern "C" void kernel_launch(void* const* d_in, const int* in_sizes, int n_in,
                              void* d_out, int out_size, void* d_ws, size_t ws_size,
                              hipStream_t stream) {
    const float* x    = (const float*)d_in[0];
    const float* w    = (const float*)d_in[1];
    const float* bias = (const float*)d_in[2];
    const int* erow   = (const int*)d_in[3];
    const int* ecol   = (const int*)d_in[4];
    const float* eval = (const float*)d_in[5];

    const int n_nodes = in_sizes[0] / D;   // 100000
    const int n_edges = in_sizes[3];       // 3200000
    const int nb = (n_nodes + 63) >> 6;    // 1563 coarse buckets
    const int tile_sz = (n_edges + T_TILES - 1) / T_TILES;

    // Persistent workspace: support(bf16, 25.6MB) | packed | rp
    char* ws = (char*)d_ws;
    unsigned* support = (unsigned*)ws;     // n_nodes * 64 bf16x2 words
    size_t off = (size_t)n_nodes * (D / 2) * sizeof(unsigned);
    int2* packed = (int2*)(ws + off);
    off += (size_t)n_edges * sizeof(int2);
    int* rp = (int*)(ws + off);

    // Transient buffers in d_out (dead before aggregate writes it)
    char* ob = (char*)d_out;
    int2* tmp = (int2*)ob;
    size_t ooff = (size_t)n_edges * sizeof(int2);
    int* M = (int*)(ob + ooff);
    ooff += (size_t)T_TILES * nb * sizeof(int);
    int* totals = (int*)(ob + ooff);
    ooff += (size_t)(nb + 1) * sizeof(int);
    int* base = (int*)(ob + ooff);

    float* out = (float*)d_out;

    // 1. support = x @ W (bf16 output)
    gcn_gemm<<<(n_nodes + GEMM_ROWS - 1) / GEMM_ROWS, 256, 0, stream>>>(
        x, w, support, n_nodes);

    // 2. Two-phase counting split -> exact CSR (packed, rp)
    gcn_tile_hist<<<T_TILES, 1024, 0, stream>>>(erow, M, n_edges, tile_sz, nb);
    gcn_tile_offsets<<<(nb + 255) / 256, 256, 0, stream>>>(M, totals, nb);
    gcn_scan_base<<<1, 1024, 0, stream>>>(totals, base, nb);
    gcn_split<<<T_TILES, 1024, 0, stream>>>(erow, ecol, eval, M, base, tmp,
                                            n_edges, tile_sz, nb);
    gcn_bucket_fill<<<nb, 256, 0, stream>>>(tmp, base, packed, rp, n_nodes);

    // 3. Gather-aggregate: one 64-lane wave per row
    gcn_aggregate<<<(n_nodes + 7) / 8, 512, 0, stream>>>(
        support, packed, rp, bias, out, n_nodes, n_edges);
}

// Round 7
// 409.766 us; speedup vs baseline: 6.6776x; 1.2069x over previous
//
#include <hip/hip_runtime.h>

#define D 128          // D_IN == D_OUT == 128
#define GEMM_ROWS 32   // rows per block in the dense GEMM
#define NB_MAX 1600    // max coarse buckets (ceil(n_nodes/64))
#define T_TILES 256    // edge tiles for the counting split

// round-to-nearest-even fp32 -> bf16 (as low 16 bits)
__device__ __forceinline__ unsigned bf16_rne(float f) {
    const unsigned u = __float_as_uint(f);
    return (u + 0x7FFFu + ((u >> 16) & 1u)) >> 16;
}
__device__ __forceinline__ float bf_lo(unsigned u) { return __uint_as_float(u << 16); }
__device__ __forceinline__ float bf_hi(unsigned u) { return __uint_as_float(u & 0xFFFF0000u); }

// -------- Stage 1: support = x @ W  (fp32 compute, bf16 output) ------------
__global__ __launch_bounds__(256) void gcn_gemm(const float* __restrict__ x,
                                                const float* __restrict__ w,
                                                unsigned* __restrict__ support, // bf16x2 units
                                                int n_nodes) {
    __shared__ float w_lds[D][D];          // 64 KB
    __shared__ float x_lds[GEMM_ROWS][D];  // 16 KB
    const int t = threadIdx.x;

    {
        const float4* w4 = (const float4*)w;
        float4* wl = (float4*)&w_lds[0][0];
#pragma unroll
        for (int i = 0; i < 16; ++i) wl[t + 256 * i] = w4[t + 256 * i];
    }
    const long row_base = (long)blockIdx.x * GEMM_ROWS;
    {
        const float4* x4 = (const float4*)(x + row_base * D);
        float4* xl = (float4*)&x_lds[0][0];
#pragma unroll
        for (int i = 0; i < 4; ++i) xl[t + 256 * i] = x4[t + 256 * i];
    }
    __syncthreads();

    const int c = t & 31;   // cols 4c..4c+3
    const int rg = t >> 5;  // rows rg*4..rg*4+3

    float4 acc[4];
#pragma unroll
    for (int j = 0; j < 4; ++j) acc[j] = make_float4(0.f, 0.f, 0.f, 0.f);

#pragma unroll 4
    for (int k = 0; k < D; ++k) {
        const float4 wv = ((const float4*)&w_lds[k][0])[c];
#pragma unroll
        for (int j = 0; j < 4; ++j) {
            const float xv = x_lds[rg * 4 + j][k];
            acc[j].x += xv * wv.x;
            acc[j].y += xv * wv.y;
            acc[j].z += xv * wv.z;
            acc[j].w += xv * wv.w;
        }
    }

#pragma unroll
    for (int j = 0; j < 4; ++j) {
        const long r = row_base + rg * 4 + j;
        uint2 pk;
        pk.x = bf16_rne(acc[j].x) | (bf16_rne(acc[j].y) << 16);
        pk.y = bf16_rne(acc[j].z) | (bf16_rne(acc[j].w) << 16);
        ((uint2*)support)[r * 32 + c] = pk;
    }
}

// -------- Stage 2a: per-tile coarse-bucket histogram (raw counts) ----------
__global__ __launch_bounds__(1024) void gcn_tile_hist(const int* __restrict__ erow,
                                                      int* __restrict__ M,
                                                      int n_edges, int tile_sz, int nb) {
    __shared__ int h[NB_MAX];
    const int t = threadIdx.x;
    for (int i = t; i < nb; i += 1024) h[i] = 0;
    __syncthreads();
    const int beg = blockIdx.x * tile_sz;
    const int end = min(beg + tile_sz, n_edges);
    for (int e = beg + t; e < end; e += 1024)
        atomicAdd(&h[erow[e] >> 6], 1);
    __syncthreads();
    int* Mrow = M + (long)blockIdx.x * nb;
    for (int i = t; i < nb; i += 1024) Mrow[i] = h[i];
}

// -------- Stage 2b: vertical exclusive scan per bucket; totals out ---------
__global__ __launch_bounds__(256) void gcn_tile_offsets(int* __restrict__ M,
                                                        int* __restrict__ totals,
                                                        int nb) {
    const int cb = blockIdx.x * 256 + threadIdx.x;
    if (cb >= nb) return;
    int running = 0;
#pragma unroll 8
    for (int tt = 0; tt < T_TILES; ++tt) {
        int* p = M + (long)tt * nb + cb;   // coalesced across threads
        const int c = *p;
        *p = running;
        running += c;
    }
    totals[cb] = running;
}

// -------- Stage 2c: exclusive scan of bucket totals -> base[0..nb] ---------
__global__ __launch_bounds__(1024) void gcn_scan_base(const int* __restrict__ totals,
                                                      int* __restrict__ base, int nb) {
    __shared__ int sdata[1024];
    const int t = threadIdx.x;
    const int chunk = (nb + 1023) >> 10;
    const int beg = min(t * chunk, nb);
    const int end = min(beg + chunk, nb);

    int sum = 0;
    for (int i = beg; i < end; ++i) sum += totals[i];
    sdata[t] = sum;
    __syncthreads();
    for (int off = 1; off < 1024; off <<= 1) {
        const int v = (t >= off) ? sdata[t - off] : 0;
        __syncthreads();
        sdata[t] += v;
        __syncthreads();
    }
    int running = sdata[t] - sum;
    if (t == 1023) base[nb] = sdata[1023];
    for (int i = beg; i < end; ++i) {
        const int c = totals[i];
        base[i] = running;
        running += c;
    }
}

// -------- Stage 2d: scatter edges into bucket-grouped tmp ------------------
__global__ __launch_bounds__(1024) void gcn_split(const int* __restrict__ erow,
                                                  const int* __restrict__ ecol,
                                                  const float* __restrict__ eval,
                                                  const int* __restrict__ M,
                                                  const int* __restrict__ base,
                                                  int2* __restrict__ tmp,
                                                  int n_edges, int tile_sz, int nb) {
    __shared__ int off[NB_MAX];
    const int t = threadIdx.x;
    const int* Mrow = M + (long)blockIdx.x * nb;
    for (int i = t; i < nb; i += 1024) off[i] = Mrow[i] + base[i];
    __syncthreads();
    const int beg = blockIdx.x * tile_sz;
    const int end = min(beg + tile_sz, n_edges);
    for (int e = beg + t; e < end; e += 1024) {
        const int r = erow[e];
        const int pos = atomicAdd(&off[r >> 6], 1);
        const unsigned key = ((unsigned)(r & 63) << 17) | (unsigned)ecol[e];
        tmp[pos] = make_int2((int)key, __float_as_int(eval[e]));
    }
}

// -------- Stage 2e: per-bucket counting sort -> exact CSR + rp -------------
__global__ __launch_bounds__(256) void gcn_bucket_fill(const int2* __restrict__ tmp,
                                                       const int* __restrict__ base,
                                                       int2* __restrict__ packed,
                                                       int* __restrict__ rp,
                                                       int n_nodes) {
    __shared__ int hist[64];
    __shared__ int offs[64];
    const int t = threadIdx.x;
    const int cb = blockIdx.x;
    const int start = base[cb];
    const int stop = base[cb + 1];

    if (t < 64) hist[t] = 0;
    __syncthreads();
    for (int i = start + t; i < stop; i += 256)
        atomicAdd(&hist[(unsigned)tmp[i].x >> 17], 1);
    __syncthreads();
    if (t == 0) {
        int run = 0;
#pragma unroll
        for (int i = 0; i < 64; ++i) { offs[i] = run; run += hist[i]; }
    }
    __syncthreads();
    if (t < 64) {
        const int r = cb * 64 + t;
        if (r < n_nodes) rp[r] = start + offs[t];
    }
    __syncthreads();
    for (int i = start + t; i < stop; i += 256) {
        const int2 ed = tmp[i];
        const int rl = (int)((unsigned)ed.x >> 17);
        const int pos = start + atomicAdd(&offs[rl], 1);
        packed[pos] = make_int2(ed.x & 0x1FFFF, ed.y);
    }
}

// -------- Stage 3: out[r] = bias + sum v_e * support[c_e] ------------------
// One wave per row; 4 edges per VMEM instruction: 4 groups of 16 lanes, each
// lane loads uint4 (8 bf16 cols, 16B/lane = Guideline-13 sweet spot).
// Cross-group shfl_xor reduction once per row.
__global__ __launch_bounds__(512) void gcn_aggregate(const uint4* __restrict__ support4,
                                                     const int2* __restrict__ packed,
                                                     const int* __restrict__ rp,
                                                     const float* __restrict__ bias,
                                                     float* __restrict__ out,
                                                     int n_nodes, int n_edges) {
    const int t = threadIdx.x;
    const int lane = t & 63;
    const int sub = lane & 15;   // which 16B slice of the row
    const int g = lane >> 4;     // which edge of the 4-edge batch
    const int r = blockIdx.x * 8 + (t >> 6);   // 8 waves per block
    if (r >= n_nodes) return;

    const int start = rp[r];
    const int end = (r + 1 < n_nodes) ? rp[r + 1] : n_edges;

    float acc[8];
#pragma unroll
    for (int k = 0; k < 8; ++k) acc[k] = 0.f;

    for (int b = start; b < end; b += 64) {
        const int nn = min(64, end - b);
        int2 ed = make_int2(0, 0);             // c=0 for pad lanes: safe row
        if (lane < nn) ed = packed[b + lane];  // coalesced 8B/lane
        const int nbat = (nn + 3) >> 2;
#pragma unroll 2
        for (int i = 0; i < nbat; ++i) {
            const int idx = i * 4 + g;
            const int c = __shfl(ed.x, idx, 64);
            float v = __int_as_float(__shfl(ed.y, idx, 64));
            if (idx >= nn) v = 0.f;
            const uint4 pv = support4[(long)c * 16 + sub];  // 1KB/wave-instr
            acc[0] += v * bf_lo(pv.x);
            acc[1] += v * bf_hi(pv.x);
            acc[2] += v * bf_lo(pv.y);
            acc[3] += v * bf_hi(pv.y);
            acc[4] += v * bf_lo(pv.z);
            acc[5] += v * bf_hi(pv.z);
            acc[6] += v * bf_lo(pv.w);
            acc[7] += v * bf_hi(pv.w);
        }
    }

    // Reduce the 4 edge-groups (lanes sub, sub+16, sub+32, sub+48)
#pragma unroll
    for (int k = 0; k < 8; ++k) {
        acc[k] += __shfl_xor(acc[k], 16, 64);
        acc[k] += __shfl_xor(acc[k], 32, 64);
    }

    if (g == 0) {   // lanes 0..15 write cols sub*8 .. sub*8+7
        const float4 b0 = ((const float4*)bias)[sub * 2];
        const float4 b1 = ((const float4*)bias)[sub * 2 + 1];
        float4 o0 = make_float4(acc[0] + b0.x, acc[1] + b0.y, acc[2] + b0.z, acc[3] + b0.w);
        float4 o1 = make_float4(acc[4] + b1.x, acc[5] + b1.y, acc[6] + b1.z, acc[7] + b1.w);
        float4* orow = (float4*)(out + (long)r * D);
        orow[sub * 2] = o0;
        orow[sub * 2 + 1] = o1;
    }
}

extern "C" void kernel_launch(void* const* d_in, const int* in_sizes, int n_in,
                              void* d_out, int out_size, void* d_ws, size_t ws_size,
                              hipStream_t stream) {
    const float* x    = (const float*)d_in[0];
    const float* w    = (const float*)d_in[1];
    const float* bias = (const float*)d_in[2];
    const int* erow   = (const int*)d_in[3];
    const int* ecol   = (const int*)d_in[4];
    const float* eval = (const float*)d_in[5];

    const int n_nodes = in_sizes[0] / D;   // 100000
    const int n_edges = in_sizes[3];       // 3200000
    const int nb = (n_nodes + 63) >> 6;    // 1563 coarse buckets
    const int tile_sz = (n_edges + T_TILES - 1) / T_TILES;

    // Persistent workspace: support(bf16, 25.6MB) | packed | rp
    char* ws = (char*)d_ws;
    unsigned* support = (unsigned*)ws;     // n_nodes * 64 bf16x2 words
    size_t off = (size_t)n_nodes * (D / 2) * sizeof(unsigned);
    int2* packed = (int2*)(ws + off);
    off += (size_t)n_edges * sizeof(int2);
    int* rp = (int*)(ws + off);

    // Transient buffers in d_out (dead before aggregate writes it)
    char* ob = (char*)d_out;
    int2* tmp = (int2*)ob;
    size_t ooff = (size_t)n_edges * sizeof(int2);
    int* M = (int*)(ob + ooff);
    ooff += (size_t)T_TILES * nb * sizeof(int);
    int* totals = (int*)(ob + ooff);
    ooff += (size_t)(nb + 1) * sizeof(int);
    int* base = (int*)(ob + ooff);

    float* out = (float*)d_out;

    // 1. support = x @ W (bf16 output)
    gcn_gemm<<<(n_nodes + GEMM_ROWS - 1) / GEMM_ROWS, 256, 0, stream>>>(
        x, w, support, n_nodes);

    // 2. Two-phase counting split -> exact CSR (packed, rp)
    gcn_tile_hist<<<T_TILES, 1024, 0, stream>>>(erow, M, n_edges, tile_sz, nb);
    gcn_tile_offsets<<<(nb + 255) / 256, 256, 0, stream>>>(M, totals, nb);
    gcn_scan_base<<<1, 1024, 0, stream>>>(totals, base, nb);
    gcn_split<<<T_TILES, 1024, 0, stream>>>(erow, ecol, eval, M, base, tmp,
                                            n_edges, tile_sz, nb);
    gcn_bucket_fill<<<nb, 256, 0, stream>>>(tmp, base, packed, rp, n_nodes);

    // 3. Gather-aggregate: one wave per row, dwordx4 gathers
    gcn_aggregate<<<(n_nodes + 7) / 8, 512, 0, stream>>>(
        (const uint4*)support, packed, rp, bias, out, n_nodes, n_edges);
}